// Round 4
// baseline (199.713 us; speedup 1.0000x reference)
//
#include <hip/hip_runtime.h>

// CBC fused kernel, round 3b: peeled software pipeline (no redundant tail
// prefetch) + nontemporal streaming loads for the read-once x matrix.
// (3a failed to compile: __builtin_nontemporal_load needs a native vector
// type, not HIP_vector_type -> use ext_vector_type(4) for x.)
// x:[B,1024] f32, components:[5,1024] f32, reasonings:[5,3,2] f32 -> probs:[B,3].
// Memory-bound on the 128 MB x read (floor ~20.4 us at 6.3 TB/s).

#define DD 1024
#define KK 5
#define CC 3
#define F4_PER_ROW (DD / 4)            // 256 float4 per row
#define F4_PER_LANE (F4_PER_ROW / 64)  // 4 per lane
#define ROWS_PER_WAVE 4                // B=32768 / 8192 waves

typedef float vfloat4 __attribute__((ext_vector_type(4)));

__global__ __launch_bounds__(256) void cbc_kernel(
    const float* __restrict__ x,
    const float* __restrict__ comps,
    const float* __restrict__ reas,
    float* __restrict__ out,
    int B)
{
    const int lane = threadIdx.x & 63;
    const int waves_per_block = blockDim.x >> 6;
    const int wave_global = blockIdx.x * waves_per_block + (threadIdx.x >> 6);
    const int n_waves = gridDim.x * waves_per_block;

    // --- component fragments in registers: lane i owns float4 columns j*64+i ---
    vfloat4 cf[KK][F4_PER_LANE];
    const vfloat4* comps4 = (const vfloat4*)comps;
#pragma unroll
    for (int k = 0; k < KK; ++k)
#pragma unroll
        for (int j = 0; j < F4_PER_LANE; ++j)
            cf[k][j] = comps4[k * F4_PER_ROW + j * 64 + lane];

    // --- |c_k|^2, reduced once per wave ---
    float c2[KK];
#pragma unroll
    for (int k = 0; k < KK; ++k) {
        float s = 0.f;
#pragma unroll
        for (int j = 0; j < F4_PER_LANE; ++j) {
            s += cf[k][j].x * cf[k][j].x;
            s += cf[k][j].y * cf[k][j].y;
            s += cf[k][j].z * cf[k][j].z;
            s += cf[k][j].w * cf[k][j].w;
        }
#pragma unroll
        for (int off = 32; off > 0; off >>= 1)
            s += __shfl_xor(s, off, 64);
        c2[k] = s;
    }

    // --- reasoning weights (tiny, cached) ---
    float w[CC][KK], bias[CC], invden[CC];
#pragma unroll
    for (int c = 0; c < CC; ++c) {
        float nsum = 0.f, dsum = 0.f;
#pragma unroll
        for (int k = 0; k < KK; ++k) {
            float a = reas[k * (CC * 2) + c * 2 + 0];
            float b = reas[k * (CC * 2) + c * 2 + 1];
            a = fminf(fmaxf(a, 0.f), 1.f);
            b = fminf(fmaxf(b, 0.f), 1.f);
            float nk = (1.f - a) * b;
            w[c][k] = a - nk;
            nsum += nk;
            dsum += a + nk;
        }
        bias[c] = nsum;
        invden[c] = 1.f / dsum;
    }

    const vfloat4* x4 = (const vfloat4*)x;
    const int row0 = wave_global;
    if (row0 >= B) return;

    vfloat4 xv[F4_PER_LANE];
#pragma unroll
    for (int j = 0; j < F4_PER_LANE; ++j)
        xv[j] = __builtin_nontemporal_load(&x4[(size_t)row0 * F4_PER_ROW + j * 64 + lane]);

    // Peeled pipeline: iteration i prefetches row i, computes row i-1.
    // No tail re-load (the old clamped prefetch re-issued 32 MB of loads).
#pragma unroll
    for (int i = 1; i <= ROWS_PER_WAVE; ++i) {
        vfloat4 nx[F4_PER_LANE];
        const int prow = row0 + i * n_waves;
        const bool do_pf = (i < ROWS_PER_WAVE) && (prow < B);
        if (do_pf) {
#pragma unroll
            for (int j = 0; j < F4_PER_LANE; ++j)
                nx[j] = __builtin_nontemporal_load(&x4[(size_t)prow * F4_PER_ROW + j * 64 + lane]);
        }

        const int row = row0 + (i - 1) * n_waves;
        if (row < B) {
            // dot products + |x|^2
            float dot[KK];
            float x2 = 0.f;
#pragma unroll
            for (int k = 0; k < KK; ++k) dot[k] = 0.f;
#pragma unroll
            for (int j = 0; j < F4_PER_LANE; ++j) {
                const vfloat4 v = xv[j];
                x2 += v.x * v.x + v.y * v.y + v.z * v.z + v.w * v.w;
#pragma unroll
                for (int k = 0; k < KK; ++k) {
                    dot[k] += v.x * cf[k][j].x;
                    dot[k] += v.y * cf[k][j].y;
                    dot[k] += v.z * cf[k][j].z;
                    dot[k] += v.w * cf[k][j].w;
                }
            }

            // butterfly-reduce {x2, dot[0..4]} across the wave
#pragma unroll
            for (int off = 32; off > 0; off >>= 1)
                x2 += __shfl_xor(x2, off, 64);
#pragma unroll
            for (int k = 0; k < KK; ++k) {
#pragma unroll
                for (int off = 32; off > 0; off >>= 1)
                    dot[k] += __shfl_xor(dot[k], off, 64);
            }

            float sims[KK];
#pragma unroll
            for (int k = 0; k < KK; ++k) {
                float d2 = fmaxf(x2 + c2[k] - 2.f * dot[k], 0.f);
                sims[k] = __expf(-0.5f * d2);   // variance = 1
            }

            if (lane < CC) {
                const int c = lane;
                float num = bias[c];
#pragma unroll
                for (int k = 0; k < KK; ++k) num += sims[k] * w[c][k];
                out[(size_t)row * CC + c] = num * invden[c];
            }
        }

        if (do_pf) {
#pragma unroll
            for (int j = 0; j < F4_PER_LANE; ++j) xv[j] = nx[j];
        }
    }
}

extern "C" void kernel_launch(void* const* d_in, const int* in_sizes, int n_in,
                              void* d_out, int out_size, void* d_ws, size_t ws_size,
                              hipStream_t stream) {
    const float* x = (const float*)d_in[0];
    const float* comps = (const float*)d_in[1];
    const float* reas = (const float*)d_in[2];
    float* out = (float*)d_out;
    const int B = in_sizes[0] / DD;   // 32768

    // 2048 blocks x 256 threads = 8192 waves x ROWS_PER_WAVE(4) = 32768 rows.
    const int blocks = 2048;
    cbc_kernel<<<blocks, 256, 0, stream>>>(x, comps, reas, out, B);
}

// Round 5
// 192.709 us; speedup vs baseline: 1.0363x; 1.0363x over previous
//
#include <hip/hip_runtime.h>

// CBC fused kernel, round 5: revert to the R1 structure (fastest measured:
// 1024 blocks, straight grid-stride loop, plain loads — no nt, no peel),
// keeping only the expansion form |x|^2 + |c|^2 - 2 x.c (strictly fewer VALU
// ops than diff^2). x:[B,1024] f32, components:[5,1024] f32,
// reasonings:[5,3,2] f32 -> probs:[B,3] f32.
// HBM-bound on the 128 MB x read; ~14x VALU headroom per the cycle model, so
// prefetch/nt machinery only added overhead (R3b regressed 191->200).

#define DD 1024
#define KK 5
#define CC 3
#define F4_PER_ROW (DD / 4)            // 256 float4 per row
#define F4_PER_LANE (F4_PER_ROW / 64)  // 4 per lane

__global__ __launch_bounds__(256) void cbc_kernel(
    const float* __restrict__ x,
    const float* __restrict__ comps,
    const float* __restrict__ reas,
    float* __restrict__ out,
    int B)
{
    const int lane = threadIdx.x & 63;
    const int waves_per_block = blockDim.x >> 6;
    const int wave_global = blockIdx.x * waves_per_block + (threadIdx.x >> 6);
    const int n_waves = gridDim.x * waves_per_block;

    // --- component fragments in registers: lane i owns float4 columns j*64+i ---
    float4 cf[KK][F4_PER_LANE];
    const float4* comps4 = (const float4*)comps;
#pragma unroll
    for (int k = 0; k < KK; ++k)
#pragma unroll
        for (int j = 0; j < F4_PER_LANE; ++j)
            cf[k][j] = comps4[k * F4_PER_ROW + j * 64 + lane];

    // --- |c_k|^2, reduced once per wave ---
    float c2[KK];
#pragma unroll
    for (int k = 0; k < KK; ++k) {
        float s = 0.f;
#pragma unroll
        for (int j = 0; j < F4_PER_LANE; ++j) {
            s += cf[k][j].x * cf[k][j].x;
            s += cf[k][j].y * cf[k][j].y;
            s += cf[k][j].z * cf[k][j].z;
            s += cf[k][j].w * cf[k][j].w;
        }
#pragma unroll
        for (int off = 32; off > 0; off >>= 1)
            s += __shfl_xor(s, off, 64);
        c2[k] = s;
    }

    // --- reasoning weights (tiny, cached) ---
    float w[CC][KK], bias[CC], invden[CC];
#pragma unroll
    for (int c = 0; c < CC; ++c) {
        float nsum = 0.f, dsum = 0.f;
#pragma unroll
        for (int k = 0; k < KK; ++k) {
            float a = reas[k * (CC * 2) + c * 2 + 0];
            float b = reas[k * (CC * 2) + c * 2 + 1];
            a = fminf(fmaxf(a, 0.f), 1.f);
            b = fminf(fmaxf(b, 0.f), 1.f);
            float nk = (1.f - a) * b;
            w[c][k] = a - nk;
            nsum += nk;
            dsum += a + nk;
        }
        bias[c] = nsum;
        invden[c] = 1.f / dsum;
    }

    const float4* x4 = (const float4*)x;

    for (int row = wave_global; row < B; row += n_waves) {
        // dot products + |x|^2 (6 FMA-class ops per element vs 10 for diff^2)
        float dot[KK];
        float x2 = 0.f;
#pragma unroll
        for (int k = 0; k < KK; ++k) dot[k] = 0.f;
#pragma unroll
        for (int j = 0; j < F4_PER_LANE; ++j) {
            const float4 v = x4[(size_t)row * F4_PER_ROW + j * 64 + lane];
            x2 += v.x * v.x + v.y * v.y + v.z * v.z + v.w * v.w;
#pragma unroll
            for (int k = 0; k < KK; ++k) {
                dot[k] += v.x * cf[k][j].x;
                dot[k] += v.y * cf[k][j].y;
                dot[k] += v.z * cf[k][j].z;
                dot[k] += v.w * cf[k][j].w;
            }
        }

        // butterfly-reduce {x2, dot[0..4]} across the wave
#pragma unroll
        for (int off = 32; off > 0; off >>= 1)
            x2 += __shfl_xor(x2, off, 64);
#pragma unroll
        for (int k = 0; k < KK; ++k) {
#pragma unroll
            for (int off = 32; off > 0; off >>= 1)
                dot[k] += __shfl_xor(dot[k], off, 64);
        }

        float sims[KK];
#pragma unroll
        for (int k = 0; k < KK; ++k) {
            float d2 = fmaxf(x2 + c2[k] - 2.f * dot[k], 0.f);
            sims[k] = __expf(-0.5f * d2);   // variance = 1
        }

        if (lane < CC) {
            const int c = lane;
            float num = bias[c];
#pragma unroll
            for (int k = 0; k < KK; ++k) num += sims[k] * w[c][k];
            out[(size_t)row * CC + c] = num * invden[c];
        }
    }
}

extern "C" void kernel_launch(void* const* d_in, const int* in_sizes, int n_in,
                              void* d_out, int out_size, void* d_ws, size_t ws_size,
                              hipStream_t stream) {
    const float* x = (const float*)d_in[0];
    const float* comps = (const float*)d_in[1];
    const float* reas = (const float*)d_in[2];
    float* out = (float*)d_out;
    const int B = in_sizes[0] / DD;   // 32768

    // 1024 blocks x 256 threads = 4096 waves -> 8 rows/wave (grid-stride).
    // Best-measured config (R1); halves per-wave cf-setup traffic vs 2048.
    const int blocks = 1024;
    cbc_kernel<<<blocks, 256, 0, stream>>>(x, comps, reas, out, B);
}